// Round 1
// baseline (326.547 us; speedup 1.0000x reference)
//
#include <hip/hip_runtime.h>

// Problem constants (fixed by the reference).
#define BATCH   128
#define RANK    64
#define HIDDEN  4096
#define NADPT   256

// Per-block H chunk: grid.y = HIDDEN / HCHUNK = 16; 256 threads.
// Rank is split 4-ways WITHIN each wave (lanes tid&3), so each thread owns
// 4 output columns x 16 ranks -> 16 fully-unrolled float4 loads in flight.
// This quadruples wave count (2048 blocks -> 8192 waves, 4 waves/SIMD at
// <=128 VGPR) and quarters the per-thread load-chain depth vs the previous
// version (512 blocks, 2 waves/SIMD, unroll-8) which was latency-bound at
// ~7x under the HBM roofline.
#define HCHUNK  256
#define RGROUPS 4
#define RPER    (RANK / RGROUPS)   // 16

__global__ __launch_bounds__(256, 4) void PaddedLoraB_59459527246474_kernel(
    const float* __restrict__ y,      // [BATCH, RANK] f32 (harness upcasts f16->f32)
    const int*   __restrict__ wids,   // [BATCH]
    const float* __restrict__ loraB,  // [NADPT, RANK, HIDDEN] f32
    float*       __restrict__ out)    // [BATCH, HIDDEN] f32
{
    const int b   = blockIdx.x;
    const int wid = wids[b] & (NADPT - 1);   // clamp: OOB insurance only

    // Stage y[b,:] into LDS once (64 floats). Reads in the main loop are
    // 4 distinct addresses per wave -> <=2-way bank aliasing (free on wave64).
    __shared__ float ysh[RANK];
    if (threadIdx.x < RANK) {
        ysh[threadIdx.x] = y[b * RANK + threadIdx.x];
    }
    __syncthreads();

    const int g = threadIdx.x & (RGROUPS - 1);  // rank group 0..3 (in-wave)
    const int c = threadIdx.x >> 2;             // float4 column group 0..63
    const int h = blockIdx.y * HCHUNK + c * 4;

    const float* Bp = loraB + (size_t)wid * (RANK * HIDDEN)
                            + (size_t)(g * RPER) * HIDDEN + h;

    float acc0 = 0.f, acc1 = 0.f, acc2 = 0.f, acc3 = 0.f;

    // Full unroll: 16 independent global_load_dwordx4 per thread, all
    // issueable before the first vmcnt wait.
#pragma unroll
    for (int r = 0; r < RPER; ++r) {
        const float4 v = *(const float4*)(Bp + (size_t)r * HIDDEN);  // coalesced: 4x256B segs/wave
        const float yv = ysh[g * RPER + r];
        acc0 = fmaf(yv, v.x, acc0);
        acc1 = fmaf(yv, v.y, acc1);
        acc2 = fmaf(yv, v.z, acc2);
        acc3 = fmaf(yv, v.w, acc3);
    }

    // Reduce the 4 rank-groups across lanes 4c..4c+3 (xor 1, then 2).
    acc0 += __shfl_xor(acc0, 1);
    acc1 += __shfl_xor(acc1, 1);
    acc2 += __shfl_xor(acc2, 1);
    acc3 += __shfl_xor(acc3, 1);
    acc0 += __shfl_xor(acc0, 2);
    acc1 += __shfl_xor(acc1, 2);
    acc2 += __shfl_xor(acc2, 2);
    acc3 += __shfl_xor(acc3, 2);

    if (g == 0) {
        float4 o;
        o.x = 2.f * acc0;
        o.y = 2.f * acc1;
        o.z = 2.f * acc2;
        o.w = 2.f * acc3;
        *(float4*)(out + (size_t)b * HIDDEN + h) = o;
    }
}

extern "C" void kernel_launch(void* const* d_in, const int* in_sizes, int n_in,
                              void* d_out, int out_size, void* d_ws, size_t ws_size,
                              hipStream_t stream) {
    // Bind inputs by element count (distinct sizes): y=8192, wids=128,
    // lora_B=67108864. Dtypes: reference f16 tensors are provided as f32 by
    // the harness (only bf16/f32/int32 decode paths exist).
    const float* y     = nullptr;
    const int*   wids  = nullptr;
    const float* loraB = nullptr;
    for (int i = 0; i < n_in; ++i) {
        if (in_sizes[i] == BATCH * RANK)               y     = (const float*)d_in[i];
        else if (in_sizes[i] == BATCH)                 wids  = (const int*)d_in[i];
        else if (in_sizes[i] == NADPT * RANK * HIDDEN) loraB = (const float*)d_in[i];
    }
    float* out = (float*)d_out;  // [128,1,4096] f32

    dim3 grid(BATCH, HIDDEN / HCHUNK, 1);  // (128, 16)
    dim3 block(256, 1, 1);
    PaddedLoraB_59459527246474_kernel<<<grid, block, 0, stream>>>(y, wids, loraB, out);
}